// Round 1
// baseline (1631.325 us; speedup 1.0000x reference)
//
#include <hip/hip_runtime.h>
#include <math.h>

// Problem constants
#define TT 80
#define BS 8
#define NA 6
#define DMODEL 768
#define LATENT 256
#define NH 4
#define DH 192
#define FFD 1024
#define NROWS (TT*BS)   // 640

// ---------------- block reduce (256 threads, 4 waves of 64) ----------------
__device__ __forceinline__ float block_reduce_sum256(float v, float* sm4) {
#pragma unroll
    for (int off = 32; off > 0; off >>= 1) v += __shfl_down(v, off, 64);
    int lane = threadIdx.x & 63, wid = threadIdx.x >> 6;
    if (lane == 0) sm4[wid] = v;
    __syncthreads();
    float r = sm4[0] + sm4[1] + sm4[2] + sm4[3];
    __syncthreads();
    return r;
}

// ---------------- embedding + positional encoding + h0 assembly ----------------
// grid: 640 blocks (r = t*8+b), 256 threads (c = latent channel)
__global__ __launch_bounds__(256) void embed_k(
        const float* __restrict__ x, const int* __restrict__ y,
        const int* __restrict__ ind_map, const float* __restrict__ skel_W,
        const float* __restrict__ skel_b, const float* __restrict__ muQ,
        const float* __restrict__ sigQ, float* __restrict__ h0) {
    __shared__ float xrow[152];
    int r = blockIdx.x;
    int t = r >> 3, b = r & 7;
    int c = threadIdx.x;
    if (c < 150) xrow[c] = x[(b * 150 + c) * TT + t];
    __syncthreads();
    float acc = skel_b[c];
    for (int jf = 0; jf < 150; jf++) acc += xrow[jf] * skel_W[jf * 256 + c];
    int ind_t = ind_map[t * 8 + b];
    int yb = y[b * NA + ind_t];
    float cm = muQ[yb * 256 + c];
    float cs = sigQ[yb * 256 + c];
    int start = (t == 0) ? 0 : (t + 2);
    // PE: div = exp(-(c&~1) * ln(10000)/256); even c -> sin, odd -> cos
    float div = expf((float)(c & ~1) * (-9.210340371976184f / 256.0f));
    float p0, p1, p2;
    if (c & 1) {
        p0 = cosf((float)start * div);
        p1 = cosf((float)(start + 1) * div);
        p2 = cosf((float)(start + 2) * div);
    } else {
        p0 = sinf((float)start * div);
        p1 = sinf((float)(start + 1) * div);
        p2 = sinf((float)(start + 2) * div);
    }
    float* hr = h0 + (size_t)r * DMODEL;
    hr[c]       = cm  + p0;
    hr[c + 256] = cs  + p1;
    hr[c + 512] = acc + p2;
}

// ---------------- generic tiled f32 GEMM: C = epi(A@B + bias) (+resid) ----------------
// EPI: 0 = none, 1 = elu+1 (linear-attention feature map), 2 = relu
// tile 64x64, 256 threads, 4x4 micro-tile. M,N,K multiples of 64/64/16.
template <int EPI>
__global__ __launch_bounds__(256) void gemm_k(
        const float* __restrict__ A, const float* __restrict__ B,
        const float* __restrict__ bias, const float* __restrict__ resid,
        float* __restrict__ C, int M, int N, int K) {
    __shared__ __attribute__((aligned(16))) float As[16][64];
    __shared__ __attribute__((aligned(16))) float Bs[16][64];
    int tid = threadIdx.x;
    int tx = tid & 15, ty = tid >> 4;
    int n0 = blockIdx.x * 64, m0 = blockIdx.y * 64;
    float acc[4][4] = {};
    int am = tid >> 2;            // 0..63 (row within tile)
    int ak = (tid & 3) * 4;       // 0,4,8,12 (k within tile)
    int bn = (tid & 15) * 4;      // col within tile
    int bk = tid >> 4;            // 0..15 (k within tile)
    for (int k0 = 0; k0 < K; k0 += 16) {
        float4 av = *(const float4*)&A[(size_t)(m0 + am) * K + k0 + ak];
        float4 bv = *(const float4*)&B[(size_t)(k0 + bk) * N + n0 + bn];
        __syncthreads();
        As[ak + 0][am] = av.x; As[ak + 1][am] = av.y;
        As[ak + 2][am] = av.z; As[ak + 3][am] = av.w;
        *(float4*)&Bs[bk][bn] = bv;
        __syncthreads();
#pragma unroll
        for (int kk = 0; kk < 16; kk++) {
            float ar[4], br[4];
            *(float4*)ar = *(const float4*)&As[kk][ty * 4];
            *(float4*)br = *(const float4*)&Bs[kk][tx * 4];
#pragma unroll
            for (int i = 0; i < 4; i++)
#pragma unroll
                for (int j = 0; j < 4; j++)
                    acc[i][j] += ar[i] * br[j];
        }
    }
    float bia[4];
    *(float4*)bia = *(const float4*)&bias[n0 + tx * 4];
#pragma unroll
    for (int i = 0; i < 4; i++) {
        int row = m0 + ty * 4 + i;
        float o[4];
#pragma unroll
        for (int j = 0; j < 4; j++) {
            float v = acc[i][j] + bia[j];
            if (EPI == 1) v = (v > 0.0f) ? (v + 1.0f) : expf(v);  // elu(v)+1
            if (EPI == 2) v = fmaxf(v, 0.0f);
            o[j] = v;
        }
        float* cp = &C[(size_t)row * N + n0 + tx * 4];
        if (resid) {
            float rr[4];
            *(float4*)rr = *(const float4*)&resid[(size_t)row * N + n0 + tx * 4];
#pragma unroll
            for (int j = 0; j < 4; j++) o[j] += rr[j];
        }
        *(float4*)cp = *(const float4*)o;
    }
}

// ---------------- row LayerNorm over 768 ----------------
// grid: 640 blocks, 256 threads; thread c handles cols c, c+256, c+512
__global__ __launch_bounds__(256) void ln_k(
        const float* __restrict__ in, float* __restrict__ out,
        const float* __restrict__ g, const float* __restrict__ b) {
    __shared__ float sm4[4];
    int row = blockIdx.x;
    const float* xr = in + (size_t)row * DMODEL;
    int c = threadIdx.x;
    float x0 = xr[c], x1 = xr[c + 256], x2 = xr[c + 512];
    float m = block_reduce_sum256(x0 + x1 + x2, sm4) * (1.0f / 768.0f);
    float d0 = x0 - m, d1 = x1 - m, d2 = x2 - m;
    float v = block_reduce_sum256(d0 * d0 + d1 * d1 + d2 * d2, sm4) * (1.0f / 768.0f);
    float r = rsqrtf(v + 1e-5f);
    float* orow = out + (size_t)row * DMODEL;
    orow[c]       = d0 * r * g[c]       + b[c];
    orow[c + 256] = d1 * r * g[c + 256] + b[c + 256];
    orow[c + 512] = d2 * r * g[c + 512] + b[c + 512];
}

// ---------------- linear-attention sequential scan (one layer) ----------------
// grid: 96 blocks = b(8) x head(4) x e-chunk(3 of 64); 256 threads.
// Thread (dt=tid>>4, et=tid&15) owns S[d0..d0+11][e0..e0+3] in registers.
__global__ __launch_bounds__(256) void scan_k(
        const float* __restrict__ Q, const float* __restrict__ Kf,
        const float* __restrict__ V, float* __restrict__ att) {
    __shared__ __attribute__((aligned(16))) float Kt[192];
    __shared__ __attribute__((aligned(16))) float Qt[192];
    __shared__ __attribute__((aligned(16))) float vt[64];
    __shared__ float Z[192];
    __shared__ __attribute__((aligned(16))) float part[16][64];
    __shared__ float wred[4];
    __shared__ float invs;
    int bx = blockIdx.x;
    int b = bx / 12, rem = bx % 12;
    int hh = rem / 3, ec = rem % 3;
    int tid = threadIdx.x;
    int dt = tid >> 4, et = tid & 15;
    int d0 = dt * 12;
    int lane = tid & 63, wid = tid >> 6;
    float4 S4[12];
#pragma unroll
    for (int i = 0; i < 12; i++) S4[i] = make_float4(0.f, 0.f, 0.f, 0.f);
    if (tid < 192) Z[tid] = 0.0f;

    for (int t = 0; t < TT; t++) {
        __syncthreads();  // protect Kt/Qt/vt/part reuse from previous iter
        int base = (t * 8 + b) * DMODEL + hh * DH;
        if (tid < 192) {
            Kt[tid] = Kf[base + tid];
            Qt[tid] = Q[base + tid];
        } else {
            vt[tid - 192] = V[base + ec * 64 + (tid - 192)];
        }
        __syncthreads();
        // Z update + denominator partial (waves 0..2 cover d=0..191)
        float pd = 0.0f;
        if (tid < 192) {
            float z = Z[tid] + Kt[tid];
            Z[tid] = z;
            pd = Qt[tid] * z;
        }
#pragma unroll
        for (int off = 32; off > 0; off >>= 1) pd += __shfl_down(pd, off, 64);
        if (lane == 0) wred[wid] = pd;
        // S update + contraction
        float4 v4 = *(const float4*)&vt[et * 4];
        float4 p4 = make_float4(0.f, 0.f, 0.f, 0.f);
#pragma unroll
        for (int i = 0; i < 12; i++) {
            float kd = Kt[d0 + i];
            float qd = Qt[d0 + i];
            S4[i].x += kd * v4.x; S4[i].y += kd * v4.y;
            S4[i].z += kd * v4.z; S4[i].w += kd * v4.w;
            p4.x += qd * S4[i].x; p4.y += qd * S4[i].y;
            p4.z += qd * S4[i].z; p4.w += qd * S4[i].w;
        }
        *(float4*)&part[dt][et * 4] = p4;
        __syncthreads();
        if (tid == 0) invs = 1.0f / (wred[0] + wred[1] + wred[2] + 1e-6f);
        __syncthreads();
        if (tid < 64) {
            float s = 0.0f;
#pragma unroll
            for (int d2 = 0; d2 < 16; d2++) s += part[d2][tid];
            att[base + ec * 64 + tid] = invs * s;
        }
    }
}

// ---------------- final LN + output gather ----------------
// grid: 48 blocks (ba = b*6+a), 256 threads
__global__ __launch_bounds__(256) void final_k(
        const float* __restrict__ h, const int* __restrict__ act_ts,
        const float* __restrict__ g, const float* __restrict__ bb,
        float* __restrict__ out) {
    __shared__ float sm4[4];
    int ba = blockIdx.x;
    int b = ba / NA;
    int ts = act_ts[ba];
    int t = ts - 1; if (t < 0) t = 0;
    const float* xr = h + (size_t)(t * 8 + b) * DMODEL;
    int c = threadIdx.x;
    float x0 = xr[c], x1 = xr[c + 256], x2 = xr[c + 512];
    float m = block_reduce_sum256(x0 + x1 + x2, sm4) * (1.0f / 768.0f);
    float d0 = x0 - m, d1 = x1 - m, d2 = x2 - m;
    float v = block_reduce_sum256(d0 * d0 + d1 * d1 + d2 * d2, sm4) * (1.0f / 768.0f);
    float r = rsqrtf(v + 1e-5f);
    out[ba * 256 + c]               = d0 * r * g[c]       + bb[c];        // mu
    out[48 * 256 + ba * 256 + c]    = d1 * r * g[c + 256] + bb[c + 256];  // logvar
}

extern "C" void kernel_launch(void* const* d_in, const int* in_sizes, int n_in,
                              void* d_out, int out_size, void* d_ws, size_t ws_size,
                              hipStream_t stream) {
    const float* x       = (const float*)d_in[0];
    const int*   y       = (const int*)d_in[1];
    const int*   ind_map = (const int*)d_in[2];
    const int*   act_ts  = (const int*)d_in[3];
    const float* skel_W  = (const float*)d_in[4];
    const float* skel_b  = (const float*)d_in[5];
    const float* muQ     = (const float*)d_in[6];
    const float* sigQ    = (const float*)d_in[7];
    const float* Wq = (const float*)d_in[8];   const float* bq = (const float*)d_in[9];
    const float* Wk = (const float*)d_in[10];  const float* bk = (const float*)d_in[11];
    const float* Wv = (const float*)d_in[12];  const float* bv = (const float*)d_in[13];
    const float* Wo = (const float*)d_in[14];  const float* bo = (const float*)d_in[15];
    const float* W1 = (const float*)d_in[16];  const float* b1 = (const float*)d_in[17];
    const float* W2 = (const float*)d_in[18];  const float* b2 = (const float*)d_in[19];
    const float* ln1_g = (const float*)d_in[20]; const float* ln1_b = (const float*)d_in[21];
    const float* ln2_g = (const float*)d_in[22]; const float* ln2_b = (const float*)d_in[23];
    const float* lnf_g = (const float*)d_in[24]; const float* lnf_b = (const float*)d_in[25];
    float* out = (float*)d_out;

    const size_t R = (size_t)NROWS * DMODEL;  // 491520 floats
    float* ws   = (float*)d_ws;
    float* h    = ws;            // current hidden state [640,768]
    float* h1   = h    + R;
    float* Qb   = h1   + R;
    float* Kb   = Qb   + R;
    float* Vb   = Kb   + R;
    float* attb = Vb   + R;
    float* tmp  = attb + R;
    float* ffn1 = tmp  + R;      // [640,1024]

    embed_k<<<NROWS, 256, 0, stream>>>(x, y, ind_map, skel_W, skel_b, muQ, sigQ, h);

    dim3 g768(12, 10);   // N/64, M/64
    dim3 g1024(16, 10);
    for (int l = 0; l < 4; l++) {
        const float* wq = Wq + (size_t)l * DMODEL * DMODEL;
        const float* wk = Wk + (size_t)l * DMODEL * DMODEL;
        const float* wv = Wv + (size_t)l * DMODEL * DMODEL;
        const float* wo = Wo + (size_t)l * DMODEL * DMODEL;
        const float* w1 = W1 + (size_t)l * DMODEL * FFD;
        const float* w2 = W2 + (size_t)l * FFD * DMODEL;
        gemm_k<1><<<g768, 256, 0, stream>>>(h, wq, bq + l * DMODEL, nullptr, Qb, NROWS, DMODEL, DMODEL);
        gemm_k<1><<<g768, 256, 0, stream>>>(h, wk, bk + l * DMODEL, nullptr, Kb, NROWS, DMODEL, DMODEL);
        gemm_k<0><<<g768, 256, 0, stream>>>(h, wv, bv + l * DMODEL, nullptr, Vb, NROWS, DMODEL, DMODEL);
        scan_k<<<96, 256, 0, stream>>>(Qb, Kb, Vb, attb);
        gemm_k<0><<<g768, 256, 0, stream>>>(attb, wo, bo + l * DMODEL, h, tmp, NROWS, DMODEL, DMODEL);
        ln_k<<<NROWS, 256, 0, stream>>>(tmp, h1, ln1_g + l * DMODEL, ln1_b + l * DMODEL);
        gemm_k<2><<<g1024, 256, 0, stream>>>(h1, w1, b1 + l * FFD, nullptr, ffn1, NROWS, FFD, DMODEL);
        gemm_k<0><<<g768, 256, 0, stream>>>(ffn1, w2, b2 + l * DMODEL, h1, tmp, NROWS, DMODEL, FFD);
        ln_k<<<NROWS, 256, 0, stream>>>(tmp, h, ln2_g + l * DMODEL, ln2_b + l * DMODEL);
    }

    final_k<<<48, 256, 0, stream>>>(h, act_ts, lnf_g, lnf_b, out);
}

// Round 3
// 748.899 us; speedup vs baseline: 2.1783x; 2.1783x over previous
//
#include <hip/hip_runtime.h>
#include <math.h>

// Problem constants
#define TT 80
#define BS 8
#define NA 6
#define DMODEL 768
#define NH 4
#define DH 192
#define FFD 1024
#define NROWS (TT*BS)   // 640
#define NQKV (3*DMODEL) // 2304

typedef __bf16 bf16;
typedef __bf16 bf16x8 __attribute__((ext_vector_type(8)));
typedef float  f32x4  __attribute__((ext_vector_type(4)));

// ---------------- block reduce (256 threads, 4 waves of 64) ----------------
__device__ __forceinline__ float block_reduce_sum256(float v, float* sm4) {
#pragma unroll
    for (int off = 32; off > 0; off >>= 1) v += __shfl_down(v, off, 64);
    int lane = threadIdx.x & 63, wid = threadIdx.x >> 6;
    if (lane == 0) sm4[wid] = v;
    __syncthreads();
    float r = sm4[0] + sm4[1] + sm4[2] + sm4[3];
    __syncthreads();
    return r;
}

// ---------------- embedding + positional encoding + h0 (f32 + bf16) ----------------
__global__ __launch_bounds__(256) void embed_k(
        const float* __restrict__ x, const int* __restrict__ y,
        const int* __restrict__ ind_map, const float* __restrict__ skel_W,
        const float* __restrict__ skel_b, const float* __restrict__ muQ,
        const float* __restrict__ sigQ, float* __restrict__ h0,
        bf16* __restrict__ h0b) {
    __shared__ float xrow[152];
    int r = blockIdx.x;
    int t = r >> 3, b = r & 7;
    int c = threadIdx.x;
    if (c < 150) xrow[c] = x[(b * 150 + c) * TT + t];
    __syncthreads();
    float acc = skel_b[c];
    for (int jf = 0; jf < 150; jf++) acc += xrow[jf] * skel_W[jf * 256 + c];
    int ind_t = ind_map[t * 8 + b];
    int yb = y[b * NA + ind_t];
    float cm = muQ[yb * 256 + c];
    float cs = sigQ[yb * 256 + c];
    int start = (t == 0) ? 0 : (t + 2);
    float div = expf((float)(c & ~1) * (-9.210340371976184f / 256.0f));
    float p0, p1, p2;
    if (c & 1) {
        p0 = cosf((float)start * div);
        p1 = cosf((float)(start + 1) * div);
        p2 = cosf((float)(start + 2) * div);
    } else {
        p0 = sinf((float)start * div);
        p1 = sinf((float)(start + 1) * div);
        p2 = sinf((float)(start + 2) * div);
    }
    float* hr = h0 + (size_t)r * DMODEL;
    float v0 = cm + p0, v1 = cs + p1, v2 = acc + p2;
    hr[c] = v0; hr[c + 256] = v1; hr[c + 512] = v2;
    bf16* hb = h0b + (size_t)r * DMODEL;
    hb[c] = (bf16)v0; hb[c + 256] = (bf16)v1; hb[c + 512] = (bf16)v2;
}

// ---------------- per-layer weight transpose + bf16 cast ----------------
// dst[n][k] = (bf16)src[k][n].  z: 0=QKV(K=768,N=2304), 1=Wo(768,768),
// 2=W1(K=768,N=1024), 3=W2(K=1024,N=768)
__global__ __launch_bounds__(256) void transpose_k(
        const float* __restrict__ wq, const float* __restrict__ wk,
        const float* __restrict__ wv, const float* __restrict__ wo,
        const float* __restrict__ w1, const float* __restrict__ w2,
        bf16* __restrict__ qkvT, bf16* __restrict__ woT,
        bf16* __restrict__ w1T, bf16* __restrict__ w2T) {
    int z = blockIdx.z;
    int K = (z == 3) ? 1024 : 768;
    int N = (z == 0) ? 2304 : (z == 2) ? 1024 : 768;
    int k0 = blockIdx.x * 32, n0 = blockIdx.y * 32;
    if (k0 >= K || n0 >= N) return;
    const float* src; bf16* dst; int ldsrc; int ncol;
    if (z == 0) {
        // NOTE: 768 is NOT a power of two — must subtract segment base,
        // `n0 & 767` is WRONG (was the R2 bug).
        if (n0 < 768)       { src = wq; ncol = n0; }
        else if (n0 < 1536) { src = wk; ncol = n0 - 768; }
        else                { src = wv; ncol = n0 - 1536; }
        dst = qkvT; ldsrc = 768;
    } else if (z == 1) { src = wo; dst = woT; ldsrc = 768;  ncol = n0; }
    else if (z == 2)   { src = w1; dst = w1T; ldsrc = 1024; ncol = n0; }
    else               { src = w2; dst = w2T; ldsrc = 768;  ncol = n0; }
    __shared__ float tile[32][33];
    int tx = threadIdx.x & 31, ty = threadIdx.x >> 5;  // 32 x 8
#pragma unroll
    for (int i = 0; i < 4; i++) {
        int r = ty + 8 * i;
        tile[r][tx] = src[(size_t)(k0 + r) * ldsrc + ncol + tx];
    }
    __syncthreads();
#pragma unroll
    for (int i = 0; i < 4; i++) {
        int r = ty + 8 * i;
        dst[(size_t)(n0 + r) * K + k0 + tx] = (bf16)tile[tx][r];
    }
}

// ---------------- bf16 MFMA GEMM: tile 64x64, 256 threads ----------------
// A [M,K] row-major bf16; Bt [N,K] row-major bf16 (i.e. B transposed).
// EPI: 0 = QKV (bias from bq/bk/bv by col segment, elu+1 on cols<1536, f32 out)
//      1 = bias + f32 resid, f32 out
//      2 = bias + relu, bf16 out
template <int EPI>
__global__ __launch_bounds__(256) void gemm_mfma(
        const bf16* __restrict__ A, const bf16* __restrict__ Bt,
        const float* __restrict__ bias_q, const float* __restrict__ bias_k,
        const float* __restrict__ bias_v, const float* __restrict__ resid,
        float* __restrict__ outF, bf16* __restrict__ outB,
        int M, int N, int K) {
    __shared__ __attribute__((aligned(16))) bf16 As[64][40];
    __shared__ __attribute__((aligned(16))) bf16 Bs[64][40];
    int tid = threadIdx.x;
    int m0 = blockIdx.y * 64, n0 = blockIdx.x * 64;
    int w = tid >> 6;           // wave id: rows w*16..w*16+15 of the tile
    int l = tid & 63;
    int lm = l & 15, lq = l >> 4;
    int sr = tid >> 2;          // staging row 0..63
    int sk = (tid & 3) * 8;     // staging k offset (bf16 elems)
    f32x4 acc[4] = {};
    for (int k0 = 0; k0 < K; k0 += 32) {
        uint4 av = *(const uint4*)&A[(size_t)(m0 + sr) * K + k0 + sk];
        uint4 bv = *(const uint4*)&Bt[(size_t)(n0 + sr) * K + k0 + sk];
        __syncthreads();
        *(uint4*)&As[sr][sk] = av;
        *(uint4*)&Bs[sr][sk] = bv;
        __syncthreads();
        bf16x8 af = *(bf16x8*)&As[w * 16 + lm][lq * 8];
#pragma unroll
        for (int nb = 0; nb < 4; nb++) {
            bf16x8 bfr = *(bf16x8*)&Bs[nb * 16 + lm][lq * 8];
            acc[nb] = __builtin_amdgcn_mfma_f32_16x16x32_bf16(af, bfr, acc[nb], 0, 0, 0);
        }
    }
    // C layout: row = (lane>>4)*4 + reg, col = lane&15
#pragma unroll
    for (int nb = 0; nb < 4; nb++) {
        int col = n0 + nb * 16 + lm;
        float b;
        bool do_elu = false;
        if (EPI == 0) {
            if (col < 768)       { b = bias_q[col];        do_elu = true; }
            else if (col < 1536) { b = bias_k[col - 768];  do_elu = true; }
            else                 { b = bias_v[col - 1536]; }
        } else {
            b = bias_q[col];
        }
#pragma unroll
        for (int r = 0; r < 4; r++) {
            int row = m0 + w * 16 + lq * 4 + r;
            float v = acc[nb][r] + b;
            if (EPI == 0) {
                if (do_elu) v = (v > 0.0f) ? (v + 1.0f) : expf(v);
                outF[(size_t)row * N + col] = v;
            } else if (EPI == 1) {
                v += resid[(size_t)row * N + col];
                outF[(size_t)row * N + col] = v;
            } else {
                v = fmaxf(v, 0.0f);
                outB[(size_t)row * N + col] = (bf16)v;
            }
        }
    }
}

// ---------------- row LayerNorm over 768 (f32 in, f32 + bf16 out) ----------------
__global__ __launch_bounds__(256) void ln_k(
        const float* __restrict__ in, float* __restrict__ outF,
        bf16* __restrict__ outB,
        const float* __restrict__ g, const float* __restrict__ b) {
    __shared__ float sm4[4];
    int row = blockIdx.x;
    const float* xr = in + (size_t)row * DMODEL;
    int c = threadIdx.x;
    float x0 = xr[c], x1 = xr[c + 256], x2 = xr[c + 512];
    float m = block_reduce_sum256(x0 + x1 + x2, sm4) * (1.0f / 768.0f);
    float d0 = x0 - m, d1 = x1 - m, d2 = x2 - m;
    float v = block_reduce_sum256(d0 * d0 + d1 * d1 + d2 * d2, sm4) * (1.0f / 768.0f);
    float r = rsqrtf(v + 1e-5f);
    float o0 = d0 * r * g[c] + b[c];
    float o1 = d1 * r * g[c + 256] + b[c + 256];
    float o2 = d2 * r * g[c + 512] + b[c + 512];
    float* orow = outF + (size_t)row * DMODEL;
    orow[c] = o0; orow[c + 256] = o1; orow[c + 512] = o2;
    bf16* brow = outB + (size_t)row * DMODEL;
    brow[c] = (bf16)o0; brow[c + 256] = (bf16)o1; brow[c + 512] = (bf16)o2;
}

// ---------------- linear-attention sequential scan (one layer) ----------------
// qkv: [row, 2304] f32 (Q | K | V).  att out: bf16 [row, 768].
// grid: 96 blocks = b(8) x head(4) x e-chunk(3 of 64); 256 threads.
__global__ __launch_bounds__(256) void scan_k(
        const float* __restrict__ qkv, bf16* __restrict__ att) {
    __shared__ __attribute__((aligned(16))) float Kt[192];
    __shared__ __attribute__((aligned(16))) float Qt[192];
    __shared__ __attribute__((aligned(16))) float vt[64];
    __shared__ float Z[192];
    __shared__ __attribute__((aligned(16))) float part[16][64];
    __shared__ float wred[4];
    __shared__ float invs;
    int bx = blockIdx.x;
    int b = bx / 12, rem = bx % 12;
    int hh = rem / 3, ec = rem % 3;
    int tid = threadIdx.x;
    int dt = tid >> 4, et = tid & 15;
    int d0 = dt * 12;
    int lane = tid & 63, wid = tid >> 6;
    float4 S4[12];
#pragma unroll
    for (int i = 0; i < 12; i++) S4[i] = make_float4(0.f, 0.f, 0.f, 0.f);
    if (tid < 192) Z[tid] = 0.0f;

    for (int t = 0; t < TT; t++) {
        __syncthreads();
        int base = (t * 8 + b) * NQKV + hh * DH;
        if (tid < 192) {
            Kt[tid] = qkv[base + 768 + tid];
            Qt[tid] = qkv[base + tid];
        } else {
            vt[tid - 192] = qkv[base + 1536 + ec * 64 + (tid - 192)];
        }
        __syncthreads();
        float pd = 0.0f;
        if (tid < 192) {
            float z = Z[tid] + Kt[tid];
            Z[tid] = z;
            pd = Qt[tid] * z;
        }
#pragma unroll
        for (int off = 32; off > 0; off >>= 1) pd += __shfl_down(pd, off, 64);
        if (lane == 0) wred[wid] = pd;
        float4 v4 = *(const float4*)&vt[et * 4];
        float4 p4 = make_float4(0.f, 0.f, 0.f, 0.f);
#pragma unroll
        for (int i = 0; i < 12; i++) {
            float kd = Kt[d0 + i];
            float qd = Qt[d0 + i];
            S4[i].x += kd * v4.x; S4[i].y += kd * v4.y;
            S4[i].z += kd * v4.z; S4[i].w += kd * v4.w;
            p4.x += qd * S4[i].x; p4.y += qd * S4[i].y;
            p4.z += qd * S4[i].z; p4.w += qd * S4[i].w;
        }
        *(float4*)&part[dt][et * 4] = p4;
        __syncthreads();
        if (tid == 0) invs = 1.0f / (wred[0] + wred[1] + wred[2] + 1e-6f);
        __syncthreads();
        if (tid < 64) {
            float s = 0.0f;
#pragma unroll
            for (int d2 = 0; d2 < 16; d2++) s += part[d2][tid];
            att[(size_t)(t * 8 + b) * DMODEL + hh * DH + ec * 64 + tid] = (bf16)(invs * s);
        }
    }
}

// ---------------- final LN + output gather ----------------
__global__ __launch_bounds__(256) void final_k(
        const float* __restrict__ h, const int* __restrict__ act_ts,
        const float* __restrict__ g, const float* __restrict__ bb,
        float* __restrict__ out) {
    __shared__ float sm4[4];
    int ba = blockIdx.x;
    int b = ba / NA;
    int ts = act_ts[ba];
    int t = ts - 1; if (t < 0) t = 0;
    const float* xr = h + (size_t)(t * 8 + b) * DMODEL;
    int c = threadIdx.x;
    float x0 = xr[c], x1 = xr[c + 256], x2 = xr[c + 512];
    float m = block_reduce_sum256(x0 + x1 + x2, sm4) * (1.0f / 768.0f);
    float d0 = x0 - m, d1 = x1 - m, d2 = x2 - m;
    float v = block_reduce_sum256(d0 * d0 + d1 * d1 + d2 * d2, sm4) * (1.0f / 768.0f);
    float r = rsqrtf(v + 1e-5f);
    out[ba * 256 + c]            = d0 * r * g[c] + bb[c];                 // mu
    out[48 * 256 + ba * 256 + c] = d1 * r * g[c + 256] + bb[c + 256];     // logvar
}

extern "C" void kernel_launch(void* const* d_in, const int* in_sizes, int n_in,
                              void* d_out, int out_size, void* d_ws, size_t ws_size,
                              hipStream_t stream) {
    const float* x       = (const float*)d_in[0];
    const int*   y       = (const int*)d_in[1];
    const int*   ind_map = (const int*)d_in[2];
    const int*   act_ts  = (const int*)d_in[3];
    const float* skel_W  = (const float*)d_in[4];
    const float* skel_b  = (const float*)d_in[5];
    const float* muQ     = (const float*)d_in[6];
    const float* sigQ    = (const float*)d_in[7];
    const float* Wq = (const float*)d_in[8];   const float* bq = (const float*)d_in[9];
    const float* Wk = (const float*)d_in[10];  const float* bk = (const float*)d_in[11];
    const float* Wv = (const float*)d_in[12];  const float* bv = (const float*)d_in[13];
    const float* Wo = (const float*)d_in[14];  const float* bo = (const float*)d_in[15];
    const float* W1 = (const float*)d_in[16];  const float* b1 = (const float*)d_in[17];
    const float* W2 = (const float*)d_in[18];  const float* b2 = (const float*)d_in[19];
    const float* ln1_g = (const float*)d_in[20]; const float* ln1_b = (const float*)d_in[21];
    const float* ln2_g = (const float*)d_in[22]; const float* ln2_b = (const float*)d_in[23];
    const float* lnf_g = (const float*)d_in[24]; const float* lnf_b = (const float*)d_in[25];
    float* out = (float*)d_out;

    // ---- workspace layout (all 16B aligned) ----
    char* p = (char*)d_ws;
    const size_t R  = (size_t)NROWS * DMODEL;      // 491520
    float* h    = (float*)p; p += R * 4;
    float* h1   = (float*)p; p += R * 4;
    float* tmp  = (float*)p; p += R * 4;
    float* qkv  = (float*)p; p += (size_t)NROWS * NQKV * 4;
    bf16* hB    = (bf16*)p;  p += R * 2;
    bf16* h1B   = (bf16*)p;  p += R * 2;
    bf16* attB  = (bf16*)p;  p += R * 2;
    bf16* ffn1B = (bf16*)p;  p += (size_t)NROWS * FFD * 2;
    bf16* qkvT  = (bf16*)p;  p += (size_t)NQKV * DMODEL * 2;    // [2304,768]
    bf16* woT   = (bf16*)p;  p += (size_t)DMODEL * DMODEL * 2;  // [768,768]
    bf16* w1T   = (bf16*)p;  p += (size_t)FFD * DMODEL * 2;     // [1024,768]
    bf16* w2T   = (bf16*)p;  p += (size_t)DMODEL * FFD * 2;     // [768,1024]

    embed_k<<<NROWS, 256, 0, stream>>>(x, y, ind_map, skel_W, skel_b, muQ, sigQ, h, hB);

    dim3 gT(32, 72, 4);          // transpose: covers K<=1024, N<=2304, 4 segments
    dim3 gQKV(NQKV / 64, 10);    // (36,10)
    dim3 g768(12, 10);
    dim3 g1024(16, 10);
    for (int l = 0; l < 4; l++) {
        const float* wq = Wq + (size_t)l * DMODEL * DMODEL;
        const float* wk = Wk + (size_t)l * DMODEL * DMODEL;
        const float* wv = Wv + (size_t)l * DMODEL * DMODEL;
        const float* wo = Wo + (size_t)l * DMODEL * DMODEL;
        const float* w1 = W1 + (size_t)l * DMODEL * FFD;
        const float* w2 = W2 + (size_t)l * FFD * DMODEL;
        transpose_k<<<gT, 256, 0, stream>>>(wq, wk, wv, wo, w1, w2, qkvT, woT, w1T, w2T);
        // QKV fused: [640,768] @ [768,2304] -> qkv (elu+1 on Q,K)
        gemm_mfma<0><<<gQKV, 256, 0, stream>>>(hB, qkvT,
                bq + l * DMODEL, bk + l * DMODEL, bv + l * DMODEL,
                nullptr, qkv, nullptr, NROWS, NQKV, DMODEL);
        scan_k<<<96, 256, 0, stream>>>(qkv, attB);
        // att @ Wo + bo + h -> tmp
        gemm_mfma<1><<<g768, 256, 0, stream>>>(attB, woT,
                bo + l * DMODEL, nullptr, nullptr, h, tmp, nullptr,
                NROWS, DMODEL, DMODEL);
        ln_k<<<NROWS, 256, 0, stream>>>(tmp, h1, h1B, ln1_g + l * DMODEL, ln1_b + l * DMODEL);
        // relu(h1 @ W1 + b1) -> ffn1 (bf16)
        gemm_mfma<2><<<g1024, 256, 0, stream>>>(h1B, w1T,
                b1 + l * FFD, nullptr, nullptr, nullptr, nullptr, ffn1B,
                NROWS, FFD, DMODEL);
        // ffn1 @ W2 + b2 + h1 -> tmp
        gemm_mfma<1><<<g768, 256, 0, stream>>>(ffn1B, w2T,
                b2 + l * DMODEL, nullptr, nullptr, h1, tmp, nullptr,
                NROWS, DMODEL, FFD);
        ln_k<<<NROWS, 256, 0, stream>>>(tmp, h, hB, ln2_g + l * DMODEL, ln2_b + l * DMODEL);
    }

    final_k<<<48, 256, 0, stream>>>(h, act_ts, lnf_g, lnf_b, out);
}

// Round 4
// 453.339 us; speedup vs baseline: 3.5985x; 1.6520x over previous
//
#include <hip/hip_runtime.h>
#include <math.h>

// Problem constants
#define TT 80
#define BS 8
#define NA 6
#define DMODEL 768
#define NH 4
#define DH 192
#define FFD 1024
#define NROWS (TT*BS)   // 640
#define NQKV (3*DMODEL) // 2304

typedef __bf16 bf16;
typedef __bf16 bf16x8 __attribute__((ext_vector_type(8)));
typedef float  f32x4  __attribute__((ext_vector_type(4)));

// ---------------- block reduce (256 threads, 4 waves of 64) ----------------
__device__ __forceinline__ float block_reduce_sum256(float v, float* sm4) {
#pragma unroll
    for (int off = 32; off > 0; off >>= 1) v += __shfl_down(v, off, 64);
    int lane = threadIdx.x & 63, wid = threadIdx.x >> 6;
    if (lane == 0) sm4[wid] = v;
    __syncthreads();
    float r = sm4[0] + sm4[1] + sm4[2] + sm4[3];
    __syncthreads();
    return r;
}

// ---------------- embedding + positional encoding + h0 (f32 + bf16) ----------------
__global__ __launch_bounds__(256) void embed_k(
        const float* __restrict__ x, const int* __restrict__ y,
        const int* __restrict__ ind_map, const float* __restrict__ skel_W,
        const float* __restrict__ skel_b, const float* __restrict__ muQ,
        const float* __restrict__ sigQ, float* __restrict__ h0,
        bf16* __restrict__ h0b) {
    __shared__ float xrow[152];
    int r = blockIdx.x;
    int t = r >> 3, b = r & 7;
    int c = threadIdx.x;
    if (c < 150) xrow[c] = x[(b * 150 + c) * TT + t];
    __syncthreads();
    float acc = skel_b[c];
    for (int jf = 0; jf < 150; jf++) acc += xrow[jf] * skel_W[jf * 256 + c];
    int ind_t = ind_map[t * 8 + b];
    int yb = y[b * NA + ind_t];
    float cm = muQ[yb * 256 + c];
    float cs = sigQ[yb * 256 + c];
    int start = (t == 0) ? 0 : (t + 2);
    float div = expf((float)(c & ~1) * (-9.210340371976184f / 256.0f));
    float p0, p1, p2;
    if (c & 1) {
        p0 = cosf((float)start * div);
        p1 = cosf((float)(start + 1) * div);
        p2 = cosf((float)(start + 2) * div);
    } else {
        p0 = sinf((float)start * div);
        p1 = sinf((float)(start + 1) * div);
        p2 = sinf((float)(start + 2) * div);
    }
    float* hr = h0 + (size_t)r * DMODEL;
    float v0 = cm + p0, v1 = cs + p1, v2 = acc + p2;
    hr[c] = v0; hr[c + 256] = v1; hr[c + 512] = v2;
    bf16* hb = h0b + (size_t)r * DMODEL;
    hb[c] = (bf16)v0; hb[c + 256] = (bf16)v1; hb[c + 512] = (bf16)v2;
}

// ---------------- per-layer weight transpose + bf16 cast ----------------
__global__ __launch_bounds__(256) void transpose_k(
        const float* __restrict__ wq, const float* __restrict__ wk,
        const float* __restrict__ wv, const float* __restrict__ wo,
        const float* __restrict__ w1, const float* __restrict__ w2,
        bf16* __restrict__ qkvT, bf16* __restrict__ woT,
        bf16* __restrict__ w1T, bf16* __restrict__ w2T) {
    int z = blockIdx.z;
    int K = (z == 3) ? 1024 : 768;
    int N = (z == 0) ? 2304 : (z == 2) ? 1024 : 768;
    int k0 = blockIdx.x * 32, n0 = blockIdx.y * 32;
    if (k0 >= K || n0 >= N) return;
    const float* src; bf16* dst; int ldsrc; int ncol;
    if (z == 0) {
        // 768 is NOT a power of two — subtract segment base (R2 bug).
        if (n0 < 768)       { src = wq; ncol = n0; }
        else if (n0 < 1536) { src = wk; ncol = n0 - 768; }
        else                { src = wv; ncol = n0 - 1536; }
        dst = qkvT; ldsrc = 768;
    } else if (z == 1) { src = wo; dst = woT; ldsrc = 768;  ncol = n0; }
    else if (z == 2)   { src = w1; dst = w1T; ldsrc = 1024; ncol = n0; }
    else               { src = w2; dst = w2T; ldsrc = 768;  ncol = n0; }
    __shared__ float tile[32][33];
    int tx = threadIdx.x & 31, ty = threadIdx.x >> 5;  // 32 x 8
#pragma unroll
    for (int i = 0; i < 4; i++) {
        int r = ty + 8 * i;
        tile[r][tx] = src[(size_t)(k0 + r) * ldsrc + ncol + tx];
    }
    __syncthreads();
#pragma unroll
    for (int i = 0; i < 4; i++) {
        int r = ty + 8 * i;
        dst[(size_t)(n0 + r) * K + k0 + tx] = (bf16)tile[tx][r];
    }
}

// ---------------- bf16 MFMA GEMM: tile 64x64, 256 threads ----------------
// A [M,K] row-major bf16; Bt [N,K] row-major bf16.
// EPI: 0 = QKV (bias by col segment, elu+1 on cols<1536, bf16 out)
//      1 = bias + f32 resid, f32 out
//      2 = bias + relu, bf16 out
template <int EPI>
__global__ __launch_bounds__(256) void gemm_mfma(
        const bf16* __restrict__ A, const bf16* __restrict__ Bt,
        const float* __restrict__ bias_q, const float* __restrict__ bias_k,
        const float* __restrict__ bias_v, const float* __restrict__ resid,
        float* __restrict__ outF, bf16* __restrict__ outB,
        int M, int N, int K) {
    __shared__ __attribute__((aligned(16))) bf16 As[64][40];
    __shared__ __attribute__((aligned(16))) bf16 Bs[64][40];
    int tid = threadIdx.x;
    int m0 = blockIdx.y * 64, n0 = blockIdx.x * 64;
    int w = tid >> 6;
    int l = tid & 63;
    int lm = l & 15, lq = l >> 4;
    int sr = tid >> 2;
    int sk = (tid & 3) * 8;
    f32x4 acc[4] = {};
    for (int k0 = 0; k0 < K; k0 += 32) {
        uint4 av = *(const uint4*)&A[(size_t)(m0 + sr) * K + k0 + sk];
        uint4 bv = *(const uint4*)&Bt[(size_t)(n0 + sr) * K + k0 + sk];
        __syncthreads();
        *(uint4*)&As[sr][sk] = av;
        *(uint4*)&Bs[sr][sk] = bv;
        __syncthreads();
        bf16x8 af = *(bf16x8*)&As[w * 16 + lm][lq * 8];
#pragma unroll
        for (int nb = 0; nb < 4; nb++) {
            bf16x8 bfr = *(bf16x8*)&Bs[nb * 16 + lm][lq * 8];
            acc[nb] = __builtin_amdgcn_mfma_f32_16x16x32_bf16(af, bfr, acc[nb], 0, 0, 0);
        }
    }
#pragma unroll
    for (int nb = 0; nb < 4; nb++) {
        int col = n0 + nb * 16 + lm;
        float b;
        bool do_elu = false;
        if (EPI == 0) {
            if (col < 768)       { b = bias_q[col];        do_elu = true; }
            else if (col < 1536) { b = bias_k[col - 768];  do_elu = true; }
            else                 { b = bias_v[col - 1536]; }
        } else {
            b = bias_q[col];
        }
#pragma unroll
        for (int r = 0; r < 4; r++) {
            int row = m0 + w * 16 + lq * 4 + r;
            float v = acc[nb][r] + b;
            if (EPI == 0) {
                if (do_elu) v = (v > 0.0f) ? (v + 1.0f) : expf(v);
                outB[(size_t)row * N + col] = (bf16)v;
            } else if (EPI == 1) {
                v += resid[(size_t)row * N + col];
                outF[(size_t)row * N + col] = v;
            } else {
                v = fmaxf(v, 0.0f);
                outB[(size_t)row * N + col] = (bf16)v;
            }
        }
    }
}

// ---------------- row LayerNorm over 768 (f32 in, f32 + bf16 out) ----------------
__global__ __launch_bounds__(256) void ln_k(
        const float* __restrict__ in, float* __restrict__ outF,
        bf16* __restrict__ outB,
        const float* __restrict__ g, const float* __restrict__ b) {
    __shared__ float sm4[4];
    int row = blockIdx.x;
    const float* xr = in + (size_t)row * DMODEL;
    int c = threadIdx.x;
    float x0 = xr[c], x1 = xr[c + 256], x2 = xr[c + 512];
    float m = block_reduce_sum256(x0 + x1 + x2, sm4) * (1.0f / 768.0f);
    float d0 = x0 - m, d1 = x1 - m, d2 = x2 - m;
    float v = block_reduce_sum256(d0 * d0 + d1 * d1 + d2 * d2, sm4) * (1.0f / 768.0f);
    float r = rsqrtf(v + 1e-5f);
    float o0 = d0 * r * g[c] + b[c];
    float o1 = d1 * r * g[c + 256] + b[c + 256];
    float o2 = d2 * r * g[c + 512] + b[c + 512];
    float* orow = outF + (size_t)row * DMODEL;
    orow[c] = o0; orow[c + 256] = o1; orow[c + 512] = o2;
    bf16* brow = outB + (size_t)row * DMODEL;
    brow[c] = (bf16)o0; brow[c + 256] = (bf16)o1; brow[c + 512] = (bf16)o2;
}

// ---------------- causal linear attention as two MFMA matmuls ----------------
// Replaces the sequential scan: S_0 = 0 implies
//   att_t = sum_{tau<=t} (Q_t . K_tau) V_tau / (rowsum_tau<=t (Q_t.K_tau) + eps)
// Block per (b,h): 32 blocks x 320 threads (5 waves, wave w owns rows w*16..+15).
// Phase 1: A = Q K^T via MFMA, mask tril, rowsum in-register (16-lane xor shuffle;
//          C-row grouping by lq-quad is identical in both phases, so denominators
//          stay in registers). Phase 2: att = A_bf16 @ V^T / denom.
__global__ __launch_bounds__(320) void attn_k(
        const bf16* __restrict__ qkvB, bf16* __restrict__ att) {
    __shared__ __attribute__((aligned(16))) char smem[64000];
    bf16* Qs = (bf16*)smem;            // [80][200]  (pad 200: 2-way-only LDS banks)
    bf16* Ks = (bf16*)(smem + 32000);  // [80][200]
    bf16* Aij = (bf16*)smem;           // [80][104]  (overlays Qs after phase 1)
    bf16* VT = (bf16*)(smem + 16640);  // [192][104] (overlays Ks)

    int b = blockIdx.x >> 2, h = blockIdx.x & 3;
    int tid = threadIdx.x;
    int w = tid >> 6, l = tid & 63;
    int lm = l & 15, lq = l >> 4;

    // ---- stage Q,K to LDS; prefetch V into registers (overlaps phase 1) ----
    uint4 vreg[6];
#pragma unroll
    for (int u = 0; u < 6; u++) {
        int c = tid + 320 * u;          // 1920 uint4 chunks per matrix
        int t = c / 24, cc = c % 24;
        int d0 = cc * 8;
        size_t g = (size_t)(t * 8 + b) * NQKV + h * DH + d0;
        uint4 qv = *(const uint4*)&qkvB[g];
        uint4 kv = *(const uint4*)&qkvB[g + 768];
        vreg[u]  = *(const uint4*)&qkvB[g + 1536];
        *(uint4*)&Qs[t * 200 + d0] = qv;
        *(uint4*)&Ks[t * 200 + d0] = kv;
    }
    __syncthreads();

    // ---- phase 1: A = Q K^T ----
    f32x4 acc[5] = {};
#pragma unroll
    for (int k0 = 0; k0 < 192; k0 += 32) {
        bf16x8 af = *(bf16x8*)&Qs[(w * 16 + lm) * 200 + lq * 8 + k0];
#pragma unroll
        for (int nb = 0; nb < 5; nb++) {
            bf16x8 bfr = *(bf16x8*)&Ks[(nb * 16 + lm) * 200 + lq * 8 + k0];
            acc[nb] = __builtin_amdgcn_mfma_f32_16x16x32_bf16(af, bfr, acc[nb], 0, 0, 0);
        }
    }
    // mask tril + in-register rowsums (row t = w*16+lq*4+r, col tau = nb*16+lm)
    float mval[5][4];
    float rs[4] = {0.f, 0.f, 0.f, 0.f};
#pragma unroll
    for (int nb = 0; nb < 5; nb++)
#pragma unroll
        for (int r = 0; r < 4; r++) {
            int t = w * 16 + lq * 4 + r, tau = nb * 16 + lm;
            float v = (tau <= t) ? acc[nb][r] : 0.0f;
            mval[nb][r] = v;
            rs[r] += v;
        }
#pragma unroll
    for (int mk = 1; mk < 16; mk <<= 1)
#pragma unroll
        for (int r = 0; r < 4; r++) rs[r] += __shfl_xor(rs[r], mk, 64);
    float inv[4];
#pragma unroll
    for (int r = 0; r < 4; r++) inv[r] = 1.0f / (rs[r] + 1e-6f);

    __syncthreads();  // all waves done reading Qs/Ks before overlay

    // ---- write masked A (bf16), stage V^T, zero K-pads (cols 80..95) ----
#pragma unroll
    for (int nb = 0; nb < 5; nb++)
#pragma unroll
        for (int r = 0; r < 4; r++)
            Aij[(w * 16 + lq * 4 + r) * 104 + nb * 16 + lm] = (bf16)mval[nb][r];
    *(uint2*)&Aij[(tid >> 2) * 104 + 80 + (tid & 3) * 4] = make_uint2(0u, 0u);
#pragma unroll
    for (int u = 0; u < 6; u++) {
        int c = tid + 320 * u;
        int t = c / 24, cc = c % 24;
        int d0 = cc * 8;
        bf16 tmp8[8];
        *(uint4*)tmp8 = vreg[u];
#pragma unroll
        for (int j = 0; j < 8; j++) VT[(d0 + j) * 104 + t] = tmp8[j];
    }
    if (tid < 192) {
        *(uint4*)&VT[tid * 104 + 80] = make_uint4(0u, 0u, 0u, 0u);
        *(uint4*)&VT[tid * 104 + 88] = make_uint4(0u, 0u, 0u, 0u);
    }
    __syncthreads();

    // ---- phase 2: att = A @ V / denom ----
#pragma unroll 1
    for (int nc = 0; nc < 12; nc++) {
        f32x4 a2 = {};
#pragma unroll
        for (int k0 = 0; k0 < 96; k0 += 32) {
            bf16x8 af = *(bf16x8*)&Aij[(w * 16 + lm) * 104 + lq * 8 + k0];
            bf16x8 bfr = *(bf16x8*)&VT[(nc * 16 + lm) * 104 + lq * 8 + k0];
            a2 = __builtin_amdgcn_mfma_f32_16x16x32_bf16(af, bfr, a2, 0, 0, 0);
        }
#pragma unroll
        for (int r = 0; r < 4; r++) {
            int t = w * 16 + lq * 4 + r;
            att[(size_t)(t * 8 + b) * DMODEL + h * DH + nc * 16 + lm] =
                (bf16)(a2[r] * inv[r]);
        }
    }
}

// ---------------- final LN + output gather ----------------
__global__ __launch_bounds__(256) void final_k(
        const float* __restrict__ h, const int* __restrict__ act_ts,
        const float* __restrict__ g, const float* __restrict__ bb,
        float* __restrict__ out) {
    __shared__ float sm4[4];
    int ba = blockIdx.x;
    int b = ba / NA;
    int ts = act_ts[ba];
    int t = ts - 1; if (t < 0) t = 0;
    const float* xr = h + (size_t)(t * 8 + b) * DMODEL;
    int c = threadIdx.x;
    float x0 = xr[c], x1 = xr[c + 256], x2 = xr[c + 512];
    float m = block_reduce_sum256(x0 + x1 + x2, sm4) * (1.0f / 768.0f);
    float d0 = x0 - m, d1 = x1 - m, d2 = x2 - m;
    float v = block_reduce_sum256(d0 * d0 + d1 * d1 + d2 * d2, sm4) * (1.0f / 768.0f);
    float r = rsqrtf(v + 1e-5f);
    out[ba * 256 + c]            = d0 * r * g[c] + bb[c];                 // mu
    out[48 * 256 + ba * 256 + c] = d1 * r * g[c + 256] + bb[c + 256];     // logvar
}

extern "C" void kernel_launch(void* const* d_in, const int* in_sizes, int n_in,
                              void* d_out, int out_size, void* d_ws, size_t ws_size,
                              hipStream_t stream) {
    const float* x       = (const float*)d_in[0];
    const int*   y       = (const int*)d_in[1];
    const int*   ind_map = (const int*)d_in[2];
    const int*   act_ts  = (const int*)d_in[3];
    const float* skel_W  = (const float*)d_in[4];
    const float* skel_b  = (const float*)d_in[5];
    const float* muQ     = (const float*)d_in[6];
    const float* sigQ    = (const float*)d_in[7];
    const float* Wq = (const float*)d_in[8];   const float* bq = (const float*)d_in[9];
    const float* Wk = (const float*)d_in[10];  const float* bk = (const float*)d_in[11];
    const float* Wv = (const float*)d_in[12];  const float* bv = (const float*)d_in[13];
    const float* Wo = (const float*)d_in[14];  const float* bo = (const float*)d_in[15];
    const float* W1 = (const float*)d_in[16];  const float* b1 = (const float*)d_in[17];
    const float* W2 = (const float*)d_in[18];  const float* b2 = (const float*)d_in[19];
    const float* ln1_g = (const float*)d_in[20]; const float* ln1_b = (const float*)d_in[21];
    const float* ln2_g = (const float*)d_in[22]; const float* ln2_b = (const float*)d_in[23];
    const float* lnf_g = (const float*)d_in[24]; const float* lnf_b = (const float*)d_in[25];
    float* out = (float*)d_out;

    // ---- workspace layout (all 16B aligned) ----
    char* p = (char*)d_ws;
    const size_t R  = (size_t)NROWS * DMODEL;      // 491520
    float* h    = (float*)p; p += R * 4;
    float* h1   = (float*)p; p += R * 4;
    float* tmp  = (float*)p; p += R * 4;
    bf16* qkvB  = (bf16*)p;  p += (size_t)NROWS * NQKV * 2;
    bf16* hB    = (bf16*)p;  p += R * 2;
    bf16* h1B   = (bf16*)p;  p += R * 2;
    bf16* attB  = (bf16*)p;  p += R * 2;
    bf16* ffn1B = (bf16*)p;  p += (size_t)NROWS * FFD * 2;
    bf16* qkvT  = (bf16*)p;  p += (size_t)NQKV * DMODEL * 2;    // [2304,768]
    bf16* woT   = (bf16*)p;  p += (size_t)DMODEL * DMODEL * 2;  // [768,768]
    bf16* w1T   = (bf16*)p;  p += (size_t)FFD * DMODEL * 2;     // [1024,768]
    bf16* w2T   = (bf16*)p;  p += (size_t)DMODEL * FFD * 2;     // [768,1024]

    embed_k<<<NROWS, 256, 0, stream>>>(x, y, ind_map, skel_W, skel_b, muQ, sigQ, h, hB);

    dim3 gT(32, 72, 4);
    dim3 gQKV(NQKV / 64, 10);
    dim3 g768(12, 10);
    dim3 g1024(16, 10);
    for (int l = 0; l < 4; l++) {
        const float* wq = Wq + (size_t)l * DMODEL * DMODEL;
        const float* wk = Wk + (size_t)l * DMODEL * DMODEL;
        const float* wv = Wv + (size_t)l * DMODEL * DMODEL;
        const float* wo = Wo + (size_t)l * DMODEL * DMODEL;
        const float* w1 = W1 + (size_t)l * DMODEL * FFD;
        const float* w2 = W2 + (size_t)l * FFD * DMODEL;
        transpose_k<<<gT, 256, 0, stream>>>(wq, wk, wv, wo, w1, w2, qkvT, woT, w1T, w2T);
        // QKV fused: [640,768] @ [768,2304] -> qkvB bf16 (elu+1 on Q,K)
        gemm_mfma<0><<<gQKV, 256, 0, stream>>>(hB, qkvT,
                bq + l * DMODEL, bk + l * DMODEL, bv + l * DMODEL,
                nullptr, nullptr, qkvB, NROWS, NQKV, DMODEL);
        attn_k<<<32, 320, 0, stream>>>(qkvB, attB);
        // att @ Wo + bo + h -> tmp
        gemm_mfma<1><<<g768, 256, 0, stream>>>(attB, woT,
                bo + l * DMODEL, nullptr, nullptr, h, tmp, nullptr,
                NROWS, DMODEL, DMODEL);
        ln_k<<<NROWS, 256, 0, stream>>>(tmp, h1, h1B, ln1_g + l * DMODEL, ln1_b + l * DMODEL);
        // relu(h1 @ W1 + b1) -> ffn1 (bf16)
        gemm_mfma<2><<<g1024, 256, 0, stream>>>(h1B, w1T,
                b1 + l * FFD, nullptr, nullptr, nullptr, nullptr, ffn1B,
                NROWS, FFD, DMODEL);
        // ffn1 @ W2 + b2 + h1 -> tmp
        gemm_mfma<1><<<g768, 256, 0, stream>>>(ffn1B, w2T,
                b2 + l * DMODEL, nullptr, nullptr, h1, tmp, nullptr,
                NROWS, DMODEL, FFD);
        ln_k<<<NROWS, 256, 0, stream>>>(tmp, h, hB, ln2_g + l * DMODEL, ln2_b + l * DMODEL);
    }

    final_k<<<48, 256, 0, stream>>>(h, act_ts, lnf_g, lnf_b, out);
}

// Round 5
// 422.503 us; speedup vs baseline: 3.8611x; 1.0730x over previous
//
#include <hip/hip_runtime.h>
#include <math.h>

// Problem constants
#define TT 80
#define BS 8
#define NA 6
#define DMODEL 768
#define NH 4
#define DH 192
#define FFD 1024
#define NROWS (TT*BS)   // 640
#define NQKV (3*DMODEL) // 2304

typedef __bf16 bf16;
typedef __bf16 bf16x8 __attribute__((ext_vector_type(8)));
typedef float  f32x4  __attribute__((ext_vector_type(4)));

// ---------------- block reduce (256 threads, 4 waves of 64) ----------------
__device__ __forceinline__ float block_reduce_sum256(float v, float* sm4) {
#pragma unroll
    for (int off = 32; off > 0; off >>= 1) v += __shfl_down(v, off, 64);
    int lane = threadIdx.x & 63, wid = threadIdx.x >> 6;
    if (lane == 0) sm4[wid] = v;
    __syncthreads();
    float r = sm4[0] + sm4[1] + sm4[2] + sm4[3];
    __syncthreads();
    return r;
}

// ---------------- embedding + positional encoding + h0 (f32 + bf16) ----------------
__global__ __launch_bounds__(256) void embed_k(
        const float* __restrict__ x, const int* __restrict__ y,
        const int* __restrict__ ind_map, const float* __restrict__ skel_W,
        const float* __restrict__ skel_b, const float* __restrict__ muQ,
        const float* __restrict__ sigQ, float* __restrict__ h0,
        bf16* __restrict__ h0b) {
    __shared__ float xrow[152];
    int r = blockIdx.x;
    int t = r >> 3, b = r & 7;
    int c = threadIdx.x;
    if (c < 150) xrow[c] = x[(b * 150 + c) * TT + t];
    __syncthreads();
    float acc = skel_b[c];
    for (int jf = 0; jf < 150; jf++) acc += xrow[jf] * skel_W[jf * 256 + c];
    int ind_t = ind_map[t * 8 + b];
    int yb = y[b * NA + ind_t];
    float cm = muQ[yb * 256 + c];
    float cs = sigQ[yb * 256 + c];
    int start = (t == 0) ? 0 : (t + 2);
    float div = expf((float)(c & ~1) * (-9.210340371976184f / 256.0f));
    float p0, p1, p2;
    if (c & 1) {
        p0 = cosf((float)start * div);
        p1 = cosf((float)(start + 1) * div);
        p2 = cosf((float)(start + 2) * div);
    } else {
        p0 = sinf((float)start * div);
        p1 = sinf((float)(start + 1) * div);
        p2 = sinf((float)(start + 2) * div);
    }
    float* hr = h0 + (size_t)r * DMODEL;
    float v0 = cm + p0, v1 = cs + p1, v2 = acc + p2;
    hr[c] = v0; hr[c + 256] = v1; hr[c + 512] = v2;
    bf16* hb = h0b + (size_t)r * DMODEL;
    hb[c] = (bf16)v0; hb[c + 256] = (bf16)v1; hb[c + 512] = (bf16)v2;
}

// ---------------- ALL-layer weight transpose + bf16 cast (one dispatch) ----------
// blockIdx.z = layer*4 + type.  type: 0=QKV, 1=Wo, 2=W1, 3=W2.
// dst[n][k] = (bf16)src[k][n], per layer.
__global__ __launch_bounds__(256) void transpose_k(
        const float* __restrict__ Wq, const float* __restrict__ Wk,
        const float* __restrict__ Wv, const float* __restrict__ Wo,
        const float* __restrict__ W1, const float* __restrict__ W2,
        bf16* __restrict__ qkvT, bf16* __restrict__ woT,
        bf16* __restrict__ w1T, bf16* __restrict__ w2T) {
    int lz = blockIdx.z;
    int l = lz >> 2, z = lz & 3;
    int K = (z == 3) ? 1024 : 768;
    int N = (z == 0) ? 2304 : (z == 2) ? 1024 : 768;
    int k0 = blockIdx.x * 32, n0 = blockIdx.y * 32;
    if (k0 >= K || n0 >= N) return;
    const float* src; bf16* dst; int ldsrc; int ncol;
    if (z == 0) {
        // 768 is NOT a power of two — subtract segment base (R2 bug).
        if (n0 < 768)       { src = Wq + (size_t)l * 768 * 768; ncol = n0; }
        else if (n0 < 1536) { src = Wk + (size_t)l * 768 * 768; ncol = n0 - 768; }
        else                { src = Wv + (size_t)l * 768 * 768; ncol = n0 - 1536; }
        dst = qkvT + (size_t)l * NQKV * DMODEL; ldsrc = 768;
    } else if (z == 1) { src = Wo + (size_t)l * 768 * 768;  dst = woT + (size_t)l * 768 * 768;  ldsrc = 768;  ncol = n0; }
    else if (z == 2)   { src = W1 + (size_t)l * 768 * 1024; dst = w1T + (size_t)l * 1024 * 768; ldsrc = 1024; ncol = n0; }
    else               { src = W2 + (size_t)l * 1024 * 768; dst = w2T + (size_t)l * 768 * 1024; ldsrc = 768;  ncol = n0; }
    __shared__ float tile[32][33];
    int tx = threadIdx.x & 31, ty = threadIdx.x >> 5;  // 32 x 8
#pragma unroll
    for (int i = 0; i < 4; i++) {
        int r = ty + 8 * i;
        tile[r][tx] = src[(size_t)(k0 + r) * ldsrc + ncol + tx];
    }
    __syncthreads();
#pragma unroll
    for (int i = 0; i < 4; i++) {
        int r = ty + 8 * i;
        dst[(size_t)(n0 + r) * K + k0 + tx] = (bf16)tile[tx][r];
    }
}

// ---------------- bf16 MFMA GEMM: tile 64x64, 256 threads ----------------
// K-loop pipelined: unroll 64, register prefetch of next chunk issued right
// after the LDS-write barrier so global (L2) latency overlaps MFMA+ds_read.
// A [M,K] row-major bf16; Bt [N,K] row-major bf16.  K % 64 == 0.
// EPI: 0 = QKV (bias by col segment, elu+1 on cols<1536, bf16 out)
//      1 = bias + f32 resid, f32 out
//      2 = bias + relu, bf16 out
template <int EPI>
__global__ __launch_bounds__(256) void gemm_mfma(
        const bf16* __restrict__ A, const bf16* __restrict__ Bt,
        const float* __restrict__ bias_q, const float* __restrict__ bias_k,
        const float* __restrict__ bias_v, const float* __restrict__ resid,
        float* __restrict__ outF, bf16* __restrict__ outB,
        int M, int N, int K) {
    __shared__ __attribute__((aligned(16))) bf16 As0[64][40];
    __shared__ __attribute__((aligned(16))) bf16 As1[64][40];
    __shared__ __attribute__((aligned(16))) bf16 Bs0[64][40];
    __shared__ __attribute__((aligned(16))) bf16 Bs1[64][40];
    int tid = threadIdx.x;
    int m0 = blockIdx.y * 64, n0 = blockIdx.x * 64;
    int w = tid >> 6;
    int l = tid & 63;
    int lm = l & 15, lq = l >> 4;
    int sr = tid >> 2;          // staging row 0..63
    int sk = (tid & 3) * 8;     // staging k offset within 32-chunk
    const bf16* Arow = &A[(size_t)(m0 + sr) * K];
    const bf16* Brow = &Bt[(size_t)(n0 + sr) * K];
    f32x4 acc[4] = {};
    // prefetch chunk 0
    uint4 a0 = *(const uint4*)&Arow[sk];
    uint4 a1 = *(const uint4*)&Arow[32 + sk];
    uint4 b0 = *(const uint4*)&Brow[sk];
    uint4 b1 = *(const uint4*)&Brow[32 + sk];
    for (int k0 = 0; k0 < K; k0 += 64) {
        __syncthreads();
        *(uint4*)&As0[sr][sk] = a0;
        *(uint4*)&As1[sr][sk] = a1;
        *(uint4*)&Bs0[sr][sk] = b0;
        *(uint4*)&Bs1[sr][sk] = b1;
        __syncthreads();
        int k2 = k0 + 64; if (k2 >= K) k2 = 0;      // tail: harmless re-read
        a0 = *(const uint4*)&Arow[k2 + sk];
        a1 = *(const uint4*)&Arow[k2 + 32 + sk];
        b0 = *(const uint4*)&Brow[k2 + sk];
        b1 = *(const uint4*)&Brow[k2 + 32 + sk];
        bf16x8 af0 = *(bf16x8*)&As0[w * 16 + lm][lq * 8];
        bf16x8 af1 = *(bf16x8*)&As1[w * 16 + lm][lq * 8];
#pragma unroll
        for (int nb = 0; nb < 4; nb++) {
            bf16x8 bf0 = *(bf16x8*)&Bs0[nb * 16 + lm][lq * 8];
            acc[nb] = __builtin_amdgcn_mfma_f32_16x16x32_bf16(af0, bf0, acc[nb], 0, 0, 0);
        }
#pragma unroll
        for (int nb = 0; nb < 4; nb++) {
            bf16x8 bf1 = *(bf16x8*)&Bs1[nb * 16 + lm][lq * 8];
            acc[nb] = __builtin_amdgcn_mfma_f32_16x16x32_bf16(af1, bf1, acc[nb], 0, 0, 0);
        }
    }
#pragma unroll
    for (int nb = 0; nb < 4; nb++) {
        int col = n0 + nb * 16 + lm;
        float b;
        bool do_elu = false;
        if (EPI == 0) {
            if (col < 768)       { b = bias_q[col];        do_elu = true; }
            else if (col < 1536) { b = bias_k[col - 768];  do_elu = true; }
            else                 { b = bias_v[col - 1536]; }
        } else {
            b = bias_q[col];
        }
#pragma unroll
        for (int r = 0; r < 4; r++) {
            int row = m0 + w * 16 + lq * 4 + r;
            float v = acc[nb][r] + b;
            if (EPI == 0) {
                if (do_elu) v = (v > 0.0f) ? (v + 1.0f) : expf(v);
                outB[(size_t)row * N + col] = (bf16)v;
            } else if (EPI == 1) {
                v += resid[(size_t)row * N + col];
                outF[(size_t)row * N + col] = v;
            } else {
                v = fmaxf(v, 0.0f);
                outB[(size_t)row * N + col] = (bf16)v;
            }
        }
    }
}

// ---------------- row LayerNorm over 768: one wave per row, no barriers ------
// grid: 160 blocks x 256 threads (4 waves = 4 rows per block).
__global__ __launch_bounds__(256) void ln_k(
        const float* __restrict__ in, float* __restrict__ outF,
        bf16* __restrict__ outB,
        const float* __restrict__ g, const float* __restrict__ b) {
    int wave = threadIdx.x >> 6, lane = threadIdx.x & 63;
    int row = blockIdx.x * 4 + wave;
    const float* xr = in + (size_t)row * DMODEL;
    float4 v[3];
    float s = 0.0f;
#pragma unroll
    for (int j = 0; j < 3; j++) {
        v[j] = *(const float4*)&xr[lane * 4 + 256 * j];
        s += v[j].x + v[j].y + v[j].z + v[j].w;
    }
#pragma unroll
    for (int mk = 1; mk < 64; mk <<= 1) s += __shfl_xor(s, mk, 64);
    float m = s * (1.0f / 768.0f);
    float sq = 0.0f;
#pragma unroll
    for (int j = 0; j < 3; j++) {
        v[j].x -= m; v[j].y -= m; v[j].z -= m; v[j].w -= m;
        sq += v[j].x * v[j].x + v[j].y * v[j].y + v[j].z * v[j].z + v[j].w * v[j].w;
    }
#pragma unroll
    for (int mk = 1; mk < 64; mk <<= 1) sq += __shfl_xor(sq, mk, 64);
    float r = rsqrtf(sq * (1.0f / 768.0f) + 1e-5f);
    float* orow = outF + (size_t)row * DMODEL;
    bf16* brow = outB + (size_t)row * DMODEL;
#pragma unroll
    for (int j = 0; j < 3; j++) {
        int c = lane * 4 + 256 * j;
        float4 gg = *(const float4*)&g[c];
        float4 bb = *(const float4*)&b[c];
        float o0 = v[j].x * r * gg.x + bb.x;
        float o1 = v[j].y * r * gg.y + bb.y;
        float o2 = v[j].z * r * gg.z + bb.z;
        float o3 = v[j].w * r * gg.w + bb.w;
        *(float4*)&orow[c] = make_float4(o0, o1, o2, o3);
        bf16 tmp4[4] = {(bf16)o0, (bf16)o1, (bf16)o2, (bf16)o3};
        *(uint2*)&brow[c] = *(uint2*)tmp4;
    }
}

// ---------------- causal linear attention as two MFMA matmuls ----------------
__global__ __launch_bounds__(320) void attn_k(
        const bf16* __restrict__ qkvB, bf16* __restrict__ att) {
    __shared__ __attribute__((aligned(16))) char smem[64000];
    bf16* Qs = (bf16*)smem;            // [80][200]
    bf16* Ks = (bf16*)(smem + 32000);  // [80][200]
    bf16* Aij = (bf16*)smem;           // [80][104]  (overlays Qs after phase 1)
    bf16* VT = (bf16*)(smem + 16640);  // [192][104] (overlays Ks)

    int b = blockIdx.x >> 2, h = blockIdx.x & 3;
    int tid = threadIdx.x;
    int w = tid >> 6, l = tid & 63;
    int lm = l & 15, lq = l >> 4;

    uint4 vreg[6];
#pragma unroll
    for (int u = 0; u < 6; u++) {
        int c = tid + 320 * u;
        int t = c / 24, cc = c % 24;
        int d0 = cc * 8;
        size_t g = (size_t)(t * 8 + b) * NQKV + h * DH + d0;
        uint4 qv = *(const uint4*)&qkvB[g];
        uint4 kv = *(const uint4*)&qkvB[g + 768];
        vreg[u]  = *(const uint4*)&qkvB[g + 1536];
        *(uint4*)&Qs[t * 200 + d0] = qv;
        *(uint4*)&Ks[t * 200 + d0] = kv;
    }
    __syncthreads();

    f32x4 acc[5] = {};
#pragma unroll
    for (int k0 = 0; k0 < 192; k0 += 32) {
        bf16x8 af = *(bf16x8*)&Qs[(w * 16 + lm) * 200 + lq * 8 + k0];
#pragma unroll
        for (int nb = 0; nb < 5; nb++) {
            bf16x8 bfr = *(bf16x8*)&Ks[(nb * 16 + lm) * 200 + lq * 8 + k0];
            acc[nb] = __builtin_amdgcn_mfma_f32_16x16x32_bf16(af, bfr, acc[nb], 0, 0, 0);
        }
    }
    float mval[5][4];
    float rs[4] = {0.f, 0.f, 0.f, 0.f};
#pragma unroll
    for (int nb = 0; nb < 5; nb++)
#pragma unroll
        for (int r = 0; r < 4; r++) {
            int t = w * 16 + lq * 4 + r, tau = nb * 16 + lm;
            float v = (tau <= t) ? acc[nb][r] : 0.0f;
            mval[nb][r] = v;
            rs[r] += v;
        }
#pragma unroll
    for (int mk = 1; mk < 16; mk <<= 1)
#pragma unroll
        for (int r = 0; r < 4; r++) rs[r] += __shfl_xor(rs[r], mk, 64);
    float inv[4];
#pragma unroll
    for (int r = 0; r < 4; r++) inv[r] = 1.0f / (rs[r] + 1e-6f);

    __syncthreads();

#pragma unroll
    for (int nb = 0; nb < 5; nb++)
#pragma unroll
        for (int r = 0; r < 4; r++)
            Aij[(w * 16 + lq * 4 + r) * 104 + nb * 16 + lm] = (bf16)mval[nb][r];
    *(uint2*)&Aij[(tid >> 2) * 104 + 80 + (tid & 3) * 4] = make_uint2(0u, 0u);
#pragma unroll
    for (int u = 0; u < 6; u++) {
        int c = tid + 320 * u;
        int t = c / 24, cc = c % 24;
        int d0 = cc * 8;
        bf16 tmp8[8];
        *(uint4*)tmp8 = vreg[u];
#pragma unroll
        for (int j = 0; j < 8; j++) VT[(d0 + j) * 104 + t] = tmp8[j];
    }
    if (tid < 192) {
        *(uint4*)&VT[tid * 104 + 80] = make_uint4(0u, 0u, 0u, 0u);
        *(uint4*)&VT[tid * 104 + 88] = make_uint4(0u, 0u, 0u, 0u);
    }
    __syncthreads();

#pragma unroll 1
    for (int nc = 0; nc < 12; nc++) {
        f32x4 a2 = {};
#pragma unroll
        for (int k0 = 0; k0 < 96; k0 += 32) {
            bf16x8 af = *(bf16x8*)&Aij[(w * 16 + lm) * 104 + lq * 8 + k0];
            bf16x8 bfr = *(bf16x8*)&VT[(nc * 16 + lm) * 104 + lq * 8 + k0];
            a2 = __builtin_amdgcn_mfma_f32_16x16x32_bf16(af, bfr, a2, 0, 0, 0);
        }
#pragma unroll
        for (int r = 0; r < 4; r++) {
            int t = w * 16 + lq * 4 + r;
            att[(size_t)(t * 8 + b) * DMODEL + h * DH + nc * 16 + lm] =
                (bf16)(a2[r] * inv[r]);
        }
    }
}

// ---------------- final LN + output gather ----------------
__global__ __launch_bounds__(256) void final_k(
        const float* __restrict__ h, const int* __restrict__ act_ts,
        const float* __restrict__ g, const float* __restrict__ bb,
        float* __restrict__ out) {
    __shared__ float sm4[4];
    int ba = blockIdx.x;
    int b = ba / NA;
    int ts = act_ts[ba];
    int t = ts - 1; if (t < 0) t = 0;
    const float* xr = h + (size_t)(t * 8 + b) * DMODEL;
    int c = threadIdx.x;
    float x0 = xr[c], x1 = xr[c + 256], x2 = xr[c + 512];
    float m = block_reduce_sum256(x0 + x1 + x2, sm4) * (1.0f / 768.0f);
    float d0 = x0 - m, d1 = x1 - m, d2 = x2 - m;
    float v = block_reduce_sum256(d0 * d0 + d1 * d1 + d2 * d2, sm4) * (1.0f / 768.0f);
    float r = rsqrtf(v + 1e-5f);
    out[ba * 256 + c]            = d0 * r * g[c] + bb[c];                 // mu
    out[48 * 256 + ba * 256 + c] = d1 * r * g[c + 256] + bb[c + 256];     // logvar
}

extern "C" void kernel_launch(void* const* d_in, const int* in_sizes, int n_in,
                              void* d_out, int out_size, void* d_ws, size_t ws_size,
                              hipStream_t stream) {
    const float* x       = (const float*)d_in[0];
    const int*   y       = (const int*)d_in[1];
    const int*   ind_map = (const int*)d_in[2];
    const int*   act_ts  = (const int*)d_in[3];
    const float* skel_W  = (const float*)d_in[4];
    const float* skel_b  = (const float*)d_in[5];
    const float* muQ     = (const float*)d_in[6];
    const float* sigQ    = (const float*)d_in[7];
    const float* Wq = (const float*)d_in[8];   const float* bq = (const float*)d_in[9];
    const float* Wk = (const float*)d_in[10];  const float* bk = (const float*)d_in[11];
    const float* Wv = (const float*)d_in[12];  const float* bv = (const float*)d_in[13];
    const float* Wo = (const float*)d_in[14];  const float* bo = (const float*)d_in[15];
    const float* W1 = (const float*)d_in[16];  const float* b1 = (const float*)d_in[17];
    const float* W2 = (const float*)d_in[18];  const float* b2 = (const float*)d_in[19];
    const float* ln1_g = (const float*)d_in[20]; const float* ln1_b = (const float*)d_in[21];
    const float* ln2_g = (const float*)d_in[22]; const float* ln2_b = (const float*)d_in[23];
    const float* lnf_g = (const float*)d_in[24]; const float* lnf_b = (const float*)d_in[25];
    float* out = (float*)d_out;

    // ---- workspace layout (all 16B aligned) ----
    char* p = (char*)d_ws;
    const size_t R  = (size_t)NROWS * DMODEL;      // 491520
    float* h    = (float*)p; p += R * 4;
    float* h1   = (float*)p; p += R * 4;
    float* tmp  = (float*)p; p += R * 4;
    bf16* qkvB  = (bf16*)p;  p += (size_t)NROWS * NQKV * 2;
    bf16* hB    = (bf16*)p;  p += R * 2;
    bf16* h1B   = (bf16*)p;  p += R * 2;
    bf16* attB  = (bf16*)p;  p += R * 2;
    bf16* ffn1B = (bf16*)p;  p += (size_t)NROWS * FFD * 2;
    // per-layer transposed weights (4 layers each)
    bf16* qkvT  = (bf16*)p;  p += (size_t)4 * NQKV * DMODEL * 2;
    bf16* woT   = (bf16*)p;  p += (size_t)4 * DMODEL * DMODEL * 2;
    bf16* w1T   = (bf16*)p;  p += (size_t)4 * FFD * DMODEL * 2;
    bf16* w2T   = (bf16*)p;  p += (size_t)4 * DMODEL * FFD * 2;

    // all-layer weight prep (single dispatch, off the per-layer critical path)
    dim3 gT(32, 72, 16);
    transpose_k<<<gT, 256, 0, stream>>>(Wq, Wk, Wv, Wo, W1, W2, qkvT, woT, w1T, w2T);
    embed_k<<<NROWS, 256, 0, stream>>>(x, y, ind_map, skel_W, skel_b, muQ, sigQ, h, hB);

    dim3 gQKV(NQKV / 64, 10);
    dim3 g768(12, 10);
    dim3 g1024(16, 10);
    for (int l = 0; l < 4; l++) {
        const bf16* qkvTl = qkvT + (size_t)l * NQKV * DMODEL;
        const bf16* woTl  = woT  + (size_t)l * DMODEL * DMODEL;
        const bf16* w1Tl  = w1T  + (size_t)l * FFD * DMODEL;
        const bf16* w2Tl  = w2T  + (size_t)l * DMODEL * FFD;
        // QKV fused: [640,768] @ [768,2304] -> qkvB bf16 (elu+1 on Q,K)
        gemm_mfma<0><<<gQKV, 256, 0, stream>>>(hB, qkvTl,
                bq + l * DMODEL, bk + l * DMODEL, bv + l * DMODEL,
                nullptr, nullptr, qkvB, NROWS, NQKV, DMODEL);
        attn_k<<<32, 320, 0, stream>>>(qkvB, attB);
        // att @ Wo + bo + h -> tmp
        gemm_mfma<1><<<g768, 256, 0, stream>>>(attB, woTl,
                bo + l * DMODEL, nullptr, nullptr, h, tmp, nullptr,
                NROWS, DMODEL, DMODEL);
        ln_k<<<NROWS / 4, 256, 0, stream>>>(tmp, h1, h1B, ln1_g + l * DMODEL, ln1_b + l * DMODEL);
        // relu(h1 @ W1 + b1) -> ffn1 (bf16)
        gemm_mfma<2><<<g1024, 256, 0, stream>>>(h1B, w1Tl,
                b1 + l * FFD, nullptr, nullptr, nullptr, nullptr, ffn1B,
                NROWS, FFD, DMODEL);
        // ffn1 @ W2 + b2 + h1 -> tmp
        gemm_mfma<1><<<g768, 256, 0, stream>>>(ffn1B, w2Tl,
                b2 + l * DMODEL, nullptr, nullptr, h1, tmp, nullptr,
                NROWS, DMODEL, FFD);
        ln_k<<<NROWS / 4, 256, 0, stream>>>(tmp, h, hB, ln2_g + l * DMODEL, ln2_b + l * DMODEL);
    }

    final_k<<<48, 256, 0, stream>>>(h, act_ts, lnf_g, lnf_b, out);
}